// Round 2
// baseline (220.379 us; speedup 1.0000x reference)
//
#include <hip/hip_runtime.h>

// ---------- small float3 helpers ----------
struct F3 { float x, y, z; };
__device__ __forceinline__ F3 operator+(F3 a, F3 b){ return {a.x+b.x, a.y+b.y, a.z+b.z}; }
__device__ __forceinline__ F3 operator-(F3 a, F3 b){ return {a.x-b.x, a.y-b.y, a.z-b.z}; }
__device__ __forceinline__ F3 operator-(F3 a){ return {-a.x, -a.y, -a.z}; }
__device__ __forceinline__ F3 operator*(float s, F3 a){ return {s*a.x, s*a.y, s*a.z}; }
__device__ __forceinline__ float dot(F3 a, F3 b){ return a.x*b.x + a.y*b.y + a.z*b.z; }
__device__ __forceinline__ F3 cross(F3 a, F3 b){
  return { a.y*b.z - a.z*b.y, a.z*b.x - a.x*b.z, a.x*b.y - a.y*b.x };
}
__device__ __forceinline__ F3 nrm(F3 v){ float inv = rsqrtf(dot(v,v)); return inv*v; }
__device__ __forceinline__ float sq3(F3 v){ return dot(v,v); }
// Rodrigues: c*v + (1-c)*dot(v,k)*k + s*cross(k,v)
__device__ __forceinline__ F3 rod(F3 v, F3 k, float s, float c){
  float d = (1.0f - c) * dot(v, k);
  F3 cr = cross(k, v);
  return { c*v.x + d*k.x + s*cr.x,
           c*v.y + d*k.y + s*cr.y,
           c*v.z + d*k.z + s*cr.z };
}
// k @ R where R rows are (rx, ry, rz):  result = k.x*rx + k.y*ry + k.z*rz
__device__ __forceinline__ F3 mulR(F3 k, F3 rx, F3 ry, F3 rz){
  return { k.x*rx.x + k.y*ry.x + k.z*rz.x,
           k.x*rx.y + k.y*ry.y + k.z*rz.y,
           k.x*rx.z + k.y*ry.z + k.z*rz.z };
}

#define BLK 128

// One thread = one sample. Requires n % BLK == 0 (B = 524288 = 4096*128).
__global__ __launch_bounds__(BLK, 2)
void rodloss_kernel(const float* __restrict__ angles,
                    const float* __restrict__ coord,
                    double* __restrict__ acc)
{
  __shared__ __align__(16) float lds_a[BLK*22];   // 11264 B
  __shared__ __align__(16) float lds_c[BLK*51];   // 26112 B
  __shared__ float red[BLK/64];

  const int t = threadIdx.x;
  const long long base = (long long)blockIdx.x * BLK;

  // -------- coalesced float4 staging: global -> LDS --------
  {
    const float4* gA = (const float4*)(angles + base*22);
    float4* sA = (float4*)lds_a;
    #pragma unroll
    for (int i = 0; i < 6; ++i) {                 // 704 float4s
      int idx = t + i*BLK;
      if (idx < (BLK*22/4)) sA[idx] = gA[idx];
    }
    const float4* gC = (const float4*)(coord + base*51);
    float4* sC = (float4*)lds_c;
    #pragma unroll
    for (int i = 0; i < 13; ++i) {                // 1632 float4s
      int idx = t + i*BLK;
      if (idx < (BLK*51/4)) sC[idx] = gC[idx];
    }
  }
  __syncthreads();

  const float* A = &lds_a[t*22];
  const float* C = &lds_c[t*51];
  auto P = [&](int i) -> F3 { return { C[3*i], C[3*i+1], C[3*i+2] }; };

  // -------- torso plane fit: solve (X^T X) xt = X^T Y, then xt.z = -1 ----
  float Sx=0.f,Sy=0.f,Sz=0.f,Sxx=0.f,Sxy=0.f,Syy=0.f,Sxz=0.f,Syz=0.f;
  {
    const int TIDX[7] = {0,1,4,7,8,11,14};
    #pragma unroll
    for (int i = 0; i < 7; ++i) {
      F3 p = P(TIDX[i]);
      Sx += p.x;  Sy += p.y;  Sz += p.z;
      Sxx += p.x*p.x;  Sxy += p.x*p.y;  Syy += p.y*p.y;
      Sxz += p.x*p.z;  Syz += p.y*p.z;
    }
  }
  // Cramer on symmetric A = [[Sxx,Sxy,Sx],[Sxy,Syy,Sy],[Sx,Sy,7]], b = [Sxz,Syz,Sz]
  const float a33 = 7.0f;
  float M00 = Syy*a33 - Sy*Sy;
  float M10 = Sxy*a33 - Sx*Sy;
  float M20 = Sxy*Sy  - Sx*Syy;
  float det  = Sxx*M00 - Sxy*M10 + Sx*M20;
  float detx = Sxz*M00 - Syz*M10 + Sz*M20;
  float dety = -Sxz*M10 + Syz*(Sxx*a33 - Sx*Sx) - Sz*(Sxx*Sy - Sx*Sxy);
  float invdet = 1.0f / det;

  F3 xtv = { detx*invdet, dety*invdet, -1.0f };
  F3 p0 = P(0), p8 = P(8);
  F3 ytv = cross(p8 - p0, xtv);
  F3 ztv = cross(xtv, ytv);
  F3 xt = nrm(xtv), yt = nrm(ytv), zt = nrm(ztv);

  // cT[i] = R * cW[i]  (rows of R are xt,yt,zt)
  auto T = [&](int i) -> F3 { F3 p = P(i); return { dot(xt,p), dot(yt,p), dot(zt,p) }; };

  const F3 X_T = {1.f,0.f,0.f}, Y_T = {0.f,1.f,0.f}, Z_T = {0.f,0.f,1.f};
  float L = 0.0f;

  F3 cT8 = T(8);

  { // ---- head ----
    F3 cT9 = T(9), cT10 = T(10);
    F3 gt0 = nrm(cT9 - cT8);
    F3 gt1 = nrm(cross(gt0, cross(cT10 - cT9, -gt0)));
    float s0,c0; __sincosf(A[0], &s0, &c0);
    F3 v_HP = rod(Z_T, Y_T, s0, c0);
    F3 v_HY_pre = rod(X_T, Y_T, s0, c0);
    float s1,c1; __sincosf(A[1], &s1, &c1);
    F3 v_HY = rod(v_HY_pre, v_HP, s1, c1);
    L += sq3(gt0 - v_HP) + sq3(gt1 - v_HY);
  }

  float s6,c6; __sincosf(A[6], &s6, &c6);   // a[6] used by both arms

  { // ---- left arm ----
    F3 cT11 = T(11), cT12 = T(12), cT13 = T(13);
    F3 gt2 = nrm(cT12 - cT11);
    F3 gt3 = nrm(cT13 - cT12);
    F3 dL = cT8 - cT11;
    float s3,c3; __sincosf(A[3], &s3, &c3);
    F3 v_LSP = rod(X_T, Y_T, s3, c3);
    float s4,c4; __sincosf(A[4], &s4, &c4);
    F3 v_LSR = rod(v_LSP, nrm(cross(dL, v_LSP)), s4, c4);
    float s5,c5; __sincosf(A[5], &s5, &c5);
    F3 v_LER = rod(v_LSR, nrm(cross(dL, v_LSR)), s5, c5);
    F3 v_LEY = rod(v_LER, v_LSR, s6, c6);
    L += sq3(gt2 - v_LSR) + sq3(gt3 - v_LEY);
  }

  { // ---- right arm ----
    F3 cT14 = T(14), cT15 = T(15), cT16 = T(16);
    F3 gt4 = nrm(cT15 - cT14);
    F3 gt5 = nrm(cT16 - cT15);
    F3 dR = cT8 - cT14;
    F3 v_RSP = rod(X_T, Y_T, s6, c6);
    float s7,c7; __sincosf(A[7], &s7, &c7);
    F3 v_RSR = rod(v_RSP, nrm(cross(v_RSP, dR)), s7, c7);
    float s8,c8; __sincosf(A[8], &s8, &c8);
    F3 v_RER = rod(v_RSR, nrm(cross(v_RSR, dR)), s8, c8);
    float s9,c9; __sincosf(A[9], &s9, &c9);
    F3 v_REY = rod(v_RER, v_RSR, s9, c9);
    L += sq3(gt4 - v_RSR) + sq3(gt5 - v_REY);
  }

  { // ---- left leg + left ankle ----
    F3 cT4 = T(4), cT5 = T(5), cT6 = T(6);
    F3 gt6 = nrm(cT5 - cT4);
    F3 gt7 = nrm(cT6 - cT5);
    float s10,c10; __sincosf(A[10], &s10, &c10);
    F3 v_LHP  = rod(-Z_T, Y_T, s10, c10);
    F3 k_LHR  = rod(X_T,  Y_T, s10, c10);
    const float r = 0.70710678118654752f;
    F3 k_LHYP = rod({0.f, r, -r}, Y_T, s10, c10);
    float s11,c11; __sincosf(A[11], &s11, &c11);
    F3 v_LHR = rod(v_LHP, k_LHR, s11, c11);
    k_LHYP   = rod(k_LHYP, k_LHR, s11, c11);
    float s12,c12; __sincosf(A[12], &s12, &c12);
    F3 v_LHYP = rod(v_LHR, k_LHYP, s12, c12);
    F3 d65 = cT6 - cT5;
    float s13,c13; __sincosf(A[13], &s13, &c13);
    F3 v_LKP = rod(v_LHYP, nrm(cross(d65, -v_LHYP)), s13, c13);
    L += sq3(gt6 - v_LHYP) + sq3(gt7 - v_LKP);
    // ankle
    F3 k_LAP = nrm(cross(d65, cT4 - cT5));
    F3 k_LAR = nrm(cross(k_LAP, cT5 - cT6));
    F3 k_LAP_W = mulR(k_LAP, xt, yt, zt);
    F3 k_LAR_W = mulR(k_LAR, xt, yt, zt);
    float s18,c18; __sincosf(A[18], &s18, &c18);
    F3 v_LAP = rod(k_LAR_W, k_LAP_W, s18, c18);
    float s19,c19; __sincosf(A[19], &s19, &c19);
    F3 v_LAR = rod(k_LAP_W, v_LAP, s19, c19);
    L += v_LAP.z*v_LAP.z + v_LAR.z*v_LAR.z;
  }

  { // ---- right leg + right ankle ----
    F3 cT1 = T(1), cT2 = T(2), cT3 = T(3);
    F3 gt8 = nrm(cT2 - cT1);
    F3 gt9 = nrm(cT3 - cT2);
    float s14,c14; __sincosf(A[14], &s14, &c14);
    F3 v_RHP  = rod(-Z_T, Y_T, s14, c14);
    F3 k_RHR  = rod(X_T,  Y_T, s14, c14);
    const float r = 0.70710678118654752f;
    F3 k_RHYP = rod({0.f, r, r}, Y_T, s14, c14);
    float s15,c15; __sincosf(A[15], &s15, &c15);
    F3 v_RHR = rod(v_RHP, k_RHR, s15, c15);
    k_RHYP   = rod(k_RHYP, k_RHR, s15, c15);
    float s16,c16; __sincosf(A[16], &s16, &c16);
    F3 v_RHYP = rod(v_RHR, k_RHYP, s16, c16);
    F3 d32 = cT3 - cT2;
    float s17,c17; __sincosf(A[17], &s17, &c17);
    F3 v_RKP = rod(v_RHYP, nrm(cross(d32, -v_RHYP)), s17, c17);
    L += sq3(gt8 - v_RHYP) + sq3(gt9 - v_RKP);
    // ankle
    F3 k_RAP = nrm(cross(d32, cT1 - cT2));
    F3 k_RAR = nrm(cross(k_RAP, cT2 - cT3));
    F3 k_RAP_W = mulR(k_RAP, xt, yt, zt);
    F3 k_RAR_W = mulR(k_RAR, xt, yt, zt);
    float s20,c20; __sincosf(A[20], &s20, &c20);
    F3 v_RAP = rod(k_RAR_W, k_RAP_W, s20, c20);
    float s21,c21; __sincosf(A[21], &s21, &c21);
    F3 v_RAR = rod(k_RAP_W, v_RAP, s21, c21);
    L += v_RAP.z*v_RAP.z + v_RAR.z*v_RAR.z;
  }

  // -------- block reduction: wave64 shuffle -> LDS -> one fp64 atomic ----
  float v = L;
  #pragma unroll
  for (int m = 32; m >= 1; m >>= 1) v += __shfl_xor(v, m, 64);
  if ((t & 63) == 0) red[t >> 6] = v;
  __syncthreads();
  if (t == 0) {
    float bs = red[0] + red[1];
    atomicAdd(acc, (double)bs);
  }
}

__global__ void finalize_kernel(const double* __restrict__ acc,
                                float* __restrict__ out, double scale)
{
  out[0] = (float)(acc[0] * scale);
}

extern "C" void kernel_launch(void* const* d_in, const int* in_sizes, int n_in,
                              void* d_out, int out_size, void* d_ws, size_t ws_size,
                              hipStream_t stream)
{
  const float* angles = (const float*)d_in[0];
  const float* coord  = (const float*)d_in[1];
  float* out = (float*)d_out;
  double* acc = (double*)d_ws;

  const int n  = in_sizes[0] / 22;     // B = 524288, divisible by BLK
  const int nb = n / BLK;

  hipMemsetAsync(d_ws, 0, sizeof(double), stream);   // graph-capturable
  rodloss_kernel<<<nb, BLK, 0, stream>>>(angles, coord, acc);
  finalize_kernel<<<1, 1, 0, stream>>>(acc, out, 1.0 / (42.0 * (double)n));
}

// Round 3
// 201.911 us; speedup vs baseline: 1.0915x; 1.0915x over previous
//
#include <hip/hip_runtime.h>

// ---------- small float3 helpers ----------
struct F3 { float x, y, z; };
__device__ __forceinline__ F3 operator+(F3 a, F3 b){ return {a.x+b.x, a.y+b.y, a.z+b.z}; }
__device__ __forceinline__ F3 operator-(F3 a, F3 b){ return {a.x-b.x, a.y-b.y, a.z-b.z}; }
__device__ __forceinline__ F3 operator-(F3 a){ return {-a.x, -a.y, -a.z}; }
__device__ __forceinline__ F3 operator*(float s, F3 a){ return {s*a.x, s*a.y, s*a.z}; }
__device__ __forceinline__ float dot(F3 a, F3 b){ return a.x*b.x + a.y*b.y + a.z*b.z; }
__device__ __forceinline__ F3 cross(F3 a, F3 b){
  return { a.y*b.z - a.z*b.y, a.z*b.x - a.x*b.z, a.x*b.y - a.y*b.x };
}
__device__ __forceinline__ F3 nrm(F3 v){ float inv = rsqrtf(dot(v,v)); return inv*v; }
__device__ __forceinline__ float sq3(F3 v){ return dot(v,v); }
// Rodrigues: c*v + (1-c)*dot(v,k)*k + s*cross(k,v)
__device__ __forceinline__ F3 rod(F3 v, F3 k, float s, float c){
  float d = (1.0f - c) * dot(v, k);
  F3 cr = cross(k, v);
  return { c*v.x + d*k.x + s*cr.x,
           c*v.y + d*k.y + s*cr.y,
           c*v.z + d*k.z + s*cr.z };
}
// k @ R where R rows are (rx, ry, rz):  result = k.x*rx + k.y*ry + k.z*rz
__device__ __forceinline__ F3 mulR(F3 k, F3 rx, F3 ry, F3 rz){
  return { k.x*rx.x + k.y*ry.x + k.z*rz.x,
           k.x*rx.y + k.y*ry.y + k.z*rz.y,
           k.x*rx.z + k.y*ry.z + k.z*rz.z };
}

#define BLK 64   // one wave per block

// One thread = one sample. Requires n % BLK == 0 (B = 524288 = 8192*64).
// LDS = 64*51*4 = 13056 B/block -> 12 blocks/CU (LDS-limited) = 12 waves/CU.
__global__ __launch_bounds__(BLK, 3)
void rodloss_kernel(const float* __restrict__ angles,
                    const float* __restrict__ coord,
                    float* __restrict__ partial)
{
  __shared__ __align__(16) float lds_c[BLK*51];   // 13056 B

  const int t = threadIdx.x;
  const size_t base = (size_t)blockIdx.x * BLK;

  // -------- coords: coalesced float4 staging global -> LDS (transpose buf) --
  {
    const float4* gC = (const float4*)(coord + base*51);   // base*51*4 % 16 == 0
    float4* sC = (float4*)lds_c;
    #pragma unroll
    for (int i = 0; i < 13; ++i) {                 // 816 float4s / 64 lanes
      int idx = t + i*BLK;
      if (idx < (BLK*51/4)) sC[idx] = gC[idx];
    }
  }

  // -------- angles: per-thread float2 loads (row = 88 B, 8B-aligned) -------
  float A[22];
  {
    const float2* gA = (const float2*)(angles + (base + t) * 22);
    #pragma unroll
    for (int i = 0; i < 11; ++i) {
      float2 v = gA[i];
      A[2*i] = v.x; A[2*i+1] = v.y;
    }
  }
  __syncthreads();

  const float* C = &lds_c[t*51];
  auto P = [&](int i) -> F3 { return { C[3*i], C[3*i+1], C[3*i+2] }; };

  // -------- torso plane fit: solve (X^T X) xt = X^T Y, then xt.z = -1 ----
  float Sx=0.f,Sy=0.f,Sz=0.f,Sxx=0.f,Sxy=0.f,Syy=0.f,Sxz=0.f,Syz=0.f;
  {
    const int TIDX[7] = {0,1,4,7,8,11,14};
    #pragma unroll
    for (int i = 0; i < 7; ++i) {
      F3 p = P(TIDX[i]);
      Sx += p.x;  Sy += p.y;  Sz += p.z;
      Sxx += p.x*p.x;  Sxy += p.x*p.y;  Syy += p.y*p.y;
      Sxz += p.x*p.z;  Syz += p.y*p.z;
    }
  }
  // Cramer on symmetric A = [[Sxx,Sxy,Sx],[Sxy,Syy,Sy],[Sx,Sy,7]], b = [Sxz,Syz,Sz]
  const float a33 = 7.0f;
  float M00 = Syy*a33 - Sy*Sy;
  float M10 = Sxy*a33 - Sx*Sy;
  float M20 = Sxy*Sy  - Sx*Syy;
  float det  = Sxx*M00 - Sxy*M10 + Sx*M20;
  float detx = Sxz*M00 - Syz*M10 + Sz*M20;
  float dety = -Sxz*M10 + Syz*(Sxx*a33 - Sx*Sx) - Sz*(Sxx*Sy - Sx*Sxy);
  float invdet = 1.0f / det;

  F3 xtv = { detx*invdet, dety*invdet, -1.0f };
  F3 p0 = P(0), p8 = P(8);
  F3 ytv = cross(p8 - p0, xtv);
  F3 ztv = cross(xtv, ytv);
  F3 xt = nrm(xtv), yt = nrm(ytv), zt = nrm(ztv);

  // cT[i] = R * cW[i]  (rows of R are xt,yt,zt)
  auto T = [&](int i) -> F3 { F3 p = P(i); return { dot(xt,p), dot(yt,p), dot(zt,p) }; };

  const F3 X_T = {1.f,0.f,0.f}, Y_T = {0.f,1.f,0.f}, Z_T = {0.f,0.f,1.f};
  float L = 0.0f;

  F3 cT8 = T(8);

  { // ---- head ----
    F3 cT9 = T(9), cT10 = T(10);
    F3 gt0 = nrm(cT9 - cT8);
    F3 gt1 = nrm(cross(gt0, cross(cT10 - cT9, -gt0)));
    float s0,c0; __sincosf(A[0], &s0, &c0);
    F3 v_HP = rod(Z_T, Y_T, s0, c0);
    F3 v_HY_pre = rod(X_T, Y_T, s0, c0);
    float s1,c1; __sincosf(A[1], &s1, &c1);
    F3 v_HY = rod(v_HY_pre, v_HP, s1, c1);
    L += sq3(gt0 - v_HP) + sq3(gt1 - v_HY);
  }

  float s6,c6; __sincosf(A[6], &s6, &c6);   // a[6] used by both arms

  { // ---- left arm ----
    F3 cT11 = T(11), cT12 = T(12), cT13 = T(13);
    F3 gt2 = nrm(cT12 - cT11);
    F3 gt3 = nrm(cT13 - cT12);
    F3 dL = cT8 - cT11;
    float s3,c3; __sincosf(A[3], &s3, &c3);
    F3 v_LSP = rod(X_T, Y_T, s3, c3);
    float s4,c4; __sincosf(A[4], &s4, &c4);
    F3 v_LSR = rod(v_LSP, nrm(cross(dL, v_LSP)), s4, c4);
    float s5,c5; __sincosf(A[5], &s5, &c5);
    F3 v_LER = rod(v_LSR, nrm(cross(dL, v_LSR)), s5, c5);
    F3 v_LEY = rod(v_LER, v_LSR, s6, c6);
    L += sq3(gt2 - v_LSR) + sq3(gt3 - v_LEY);
  }

  { // ---- right arm ----
    F3 cT14 = T(14), cT15 = T(15), cT16 = T(16);
    F3 gt4 = nrm(cT15 - cT14);
    F3 gt5 = nrm(cT16 - cT15);
    F3 dR = cT8 - cT14;
    F3 v_RSP = rod(X_T, Y_T, s6, c6);
    float s7,c7; __sincosf(A[7], &s7, &c7);
    F3 v_RSR = rod(v_RSP, nrm(cross(v_RSP, dR)), s7, c7);
    float s8,c8; __sincosf(A[8], &s8, &c8);
    F3 v_RER = rod(v_RSR, nrm(cross(v_RSR, dR)), s8, c8);
    float s9,c9; __sincosf(A[9], &s9, &c9);
    F3 v_REY = rod(v_RER, v_RSR, s9, c9);
    L += sq3(gt4 - v_RSR) + sq3(gt5 - v_REY);
  }

  { // ---- left leg + left ankle ----
    F3 cT4 = T(4), cT5 = T(5), cT6 = T(6);
    F3 gt6 = nrm(cT5 - cT4);
    F3 gt7 = nrm(cT6 - cT5);
    float s10,c10; __sincosf(A[10], &s10, &c10);
    F3 v_LHP  = rod(-Z_T, Y_T, s10, c10);
    F3 k_LHR  = rod(X_T,  Y_T, s10, c10);
    const float r = 0.70710678118654752f;
    F3 k_LHYP = rod({0.f, r, -r}, Y_T, s10, c10);
    float s11,c11; __sincosf(A[11], &s11, &c11);
    F3 v_LHR = rod(v_LHP, k_LHR, s11, c11);
    k_LHYP   = rod(k_LHYP, k_LHR, s11, c11);
    float s12,c12; __sincosf(A[12], &s12, &c12);
    F3 v_LHYP = rod(v_LHR, k_LHYP, s12, c12);
    F3 d65 = cT6 - cT5;
    float s13,c13; __sincosf(A[13], &s13, &c13);
    F3 v_LKP = rod(v_LHYP, nrm(cross(d65, -v_LHYP)), s13, c13);
    L += sq3(gt6 - v_LHYP) + sq3(gt7 - v_LKP);
    // ankle
    F3 k_LAP = nrm(cross(d65, cT4 - cT5));
    F3 k_LAR = nrm(cross(k_LAP, cT5 - cT6));
    F3 k_LAP_W = mulR(k_LAP, xt, yt, zt);
    F3 k_LAR_W = mulR(k_LAR, xt, yt, zt);
    float s18,c18; __sincosf(A[18], &s18, &c18);
    F3 v_LAP = rod(k_LAR_W, k_LAP_W, s18, c18);
    float s19,c19; __sincosf(A[19], &s19, &c19);
    F3 v_LAR = rod(k_LAP_W, v_LAP, s19, c19);
    L += v_LAP.z*v_LAP.z + v_LAR.z*v_LAR.z;
  }

  { // ---- right leg + right ankle ----
    F3 cT1 = T(1), cT2 = T(2), cT3 = T(3);
    F3 gt8 = nrm(cT2 - cT1);
    F3 gt9 = nrm(cT3 - cT2);
    float s14,c14; __sincosf(A[14], &s14, &c14);
    F3 v_RHP  = rod(-Z_T, Y_T, s14, c14);
    F3 k_RHR  = rod(X_T,  Y_T, s14, c14);
    const float r = 0.70710678118654752f;
    F3 k_RHYP = rod({0.f, r, r}, Y_T, s14, c14);
    float s15,c15; __sincosf(A[15], &s15, &c15);
    F3 v_RHR = rod(v_RHP, k_RHR, s15, c15);
    k_RHYP   = rod(k_RHYP, k_RHR, s15, c15);
    float s16,c16; __sincosf(A[16], &s16, &c16);
    F3 v_RHYP = rod(v_RHR, k_RHYP, s16, c16);
    F3 d32 = cT3 - cT2;
    float s17,c17; __sincosf(A[17], &s17, &c17);
    F3 v_RKP = rod(v_RHYP, nrm(cross(d32, -v_RHYP)), s17, c17);
    L += sq3(gt8 - v_RHYP) + sq3(gt9 - v_RKP);
    // ankle
    F3 k_RAP = nrm(cross(d32, cT1 - cT2));
    F3 k_RAR = nrm(cross(k_RAP, cT2 - cT3));
    F3 k_RAP_W = mulR(k_RAP, xt, yt, zt);
    F3 k_RAR_W = mulR(k_RAR, xt, yt, zt);
    float s20,c20; __sincosf(A[20], &s20, &c20);
    F3 v_RAP = rod(k_RAR_W, k_RAP_W, s20, c20);
    float s21,c21; __sincosf(A[21], &s21, &c21);
    F3 v_RAR = rod(k_RAP_W, v_RAP, s21, c21);
    L += v_RAP.z*v_RAP.z + v_RAR.z*v_RAR.z;
  }

  // -------- wave64 shuffle reduction -> one partial per block (no atomics) --
  float v = L;
  #pragma unroll
  for (int m = 32; m >= 1; m >>= 1) v += __shfl_xor(v, m, 64);
  if (t == 0) partial[blockIdx.x] = v;
}

// Single-block final reduction: fp64 accumulate, scale, write fp32 result.
__global__ void reduce_kernel(const float* __restrict__ part, int n,
                              float* __restrict__ out, double scale)
{
  const int t = threadIdx.x;
  double s = 0.0;
  for (int i = t; i < n; i += 256) s += (double)part[i];
  #pragma unroll
  for (int m = 32; m >= 1; m >>= 1) s += __shfl_xor(s, m, 64);
  __shared__ double red[4];
  if ((t & 63) == 0) red[t >> 6] = s;
  __syncthreads();
  if (t == 0) out[0] = (float)((red[0] + red[1] + red[2] + red[3]) * scale);
}

extern "C" void kernel_launch(void* const* d_in, const int* in_sizes, int n_in,
                              void* d_out, int out_size, void* d_ws, size_t ws_size,
                              hipStream_t stream)
{
  const float* angles = (const float*)d_in[0];
  const float* coord  = (const float*)d_in[1];
  float* out = (float*)d_out;
  float* partial = (float*)d_ws;          // nb floats (32 KB) — no init needed

  const int n  = in_sizes[0] / 22;        // B = 524288, divisible by BLK
  const int nb = n / BLK;                 // 8192

  rodloss_kernel<<<nb, BLK, 0, stream>>>(angles, coord, partial);
  reduce_kernel<<<1, 256, 0, stream>>>(partial, nb, out, 1.0 / (42.0 * (double)n));
}